// Round 1
// baseline (202.517 us; speedup 1.0000x reference)
//
#include <hip/hip_runtime.h>
#include <math.h>

namespace {

constexpr int D     = 128;   // model dim
constexpr int H     = 8;     // heads
constexpr int HD    = 16;    // head dim
constexpr int TN    = 64;    // neighbor tokens (total tokens = 1 + TN)
constexpr int WAVES = 4;     // one batch element per wave
constexpr int QKP   = D + 4; // padded row (132) -> conflict-free per-head reads in pass 3

__global__ __launch_bounds__(WAVES * 64)
void mha_center_kernel(const float* __restrict__ center,
                       const float* __restrict__ neighbors,
                       const float* __restrict__ WQ,
                       const float* __restrict__ WK,
                       const float* __restrict__ WV,
                       const float* __restrict__ WO,
                       float* __restrict__ out)
{
    __shared__ float c_lds[WAVES][D];
    __shared__ float q_lds[WAVES][D];        // reused later for pre-WO "out"
    __shared__ float qk_lds[WAVES][H][QKP];  // reused later for s (weighted token sums)
    __shared__ float P_lds[WAVES][TN][H];    // attn weights for neighbor tokens

    const int w  = threadIdx.x >> 6;   // wave id within block
    const int l  = threadIdx.x & 63;   // lane
    const int b  = blockIdx.x * WAVES + w;
    const int d0 = l << 1;             // lane's two column indices: d0, d0+1

    // ---- stage center row ----
    const float2 cv = *reinterpret_cast<const float2*>(center + (size_t)b * D + d0);
    *reinterpret_cast<float2*>(&c_lds[w][d0]) = cv;
    __syncthreads();

    // ---- phase A: q = (center @ WQ) * 0.25 (hd^-0.5 folded in) ----
    float q0 = 0.f, q1 = 0.f;
    #pragma unroll 8
    for (int i4 = 0; i4 < D / 4; ++i4) {
        const float4 c4 = *reinterpret_cast<const float4*>(&c_lds[w][i4 * 4]);
        const float cc[4] = {c4.x, c4.y, c4.z, c4.w};
        #pragma unroll
        for (int u = 0; u < 4; ++u) {
            const float2 wq = *reinterpret_cast<const float2*>(WQ + (size_t)(i4 * 4 + u) * D + d0);
            q0 = fmaf(cc[u], wq.x, q0);
            q1 = fmaf(cc[u], wq.y, q1);
        }
    }
    q_lds[w][d0]     = q0 * 0.25f;
    q_lds[w][d0 + 1] = q1 * 0.25f;
    __syncthreads();

    // ---- phase B: qk[h][d] = sum_j q[h*16+j] * WK[d][h*16+j] ----
    #pragma unroll
    for (int h = 0; h < H; ++h) {
        float a0 = 0.f, a1 = 0.f;
        const float* wk0 = WK + (size_t)d0 * D + h * HD;
        const float* wk1 = wk0 + D;
        #pragma unroll
        for (int j4 = 0; j4 < HD / 4; ++j4) {
            const float4 qv = *reinterpret_cast<const float4*>(&q_lds[w][h * HD + j4 * 4]);
            const float4 k0 = *reinterpret_cast<const float4*>(wk0 + j4 * 4);
            const float4 k1 = *reinterpret_cast<const float4*>(wk1 + j4 * 4);
            a0 = fmaf(qv.x, k0.x, fmaf(qv.y, k0.y, fmaf(qv.z, k0.z, fmaf(qv.w, k0.w, a0))));
            a1 = fmaf(qv.x, k1.x, fmaf(qv.y, k1.y, fmaf(qv.z, k1.z, fmaf(qv.w, k1.w, a1))));
        }
        qk_lds[w][h][d0]     = a0;
        qk_lds[w][h][d0 + 1] = a1;
    }
    __syncthreads();

    // ---- center-token score (butterfly -> uniform across lanes) ----
    float s0[H];
    #pragma unroll
    for (int h = 0; h < H; ++h) {
        float v = qk_lds[w][h][d0] * c_lds[w][d0] + qk_lds[w][h][d0 + 1] * c_lds[w][d0 + 1];
        #pragma unroll
        for (int off = 32; off >= 1; off >>= 1)
            v += __shfl_xor(v, off);
        s0[h] = v;
    }

    // ---- pass 1: lane l computes scores for neighbor token l ----
    float sc[H];
    #pragma unroll
    for (int h = 0; h < H; ++h) sc[h] = 0.f;
    const float4* nb = reinterpret_cast<const float4*>(neighbors + ((size_t)b * TN + l) * D);
    #pragma unroll 4
    for (int dc = 0; dc < D / 4; ++dc) {
        const float4 tv = nb[dc];
        #pragma unroll
        for (int h = 0; h < H; ++h) {
            const float4 k4 = *reinterpret_cast<const float4*>(&qk_lds[w][h][dc * 4]);
            sc[h] = fmaf(tv.x, k4.x, fmaf(tv.y, k4.y, fmaf(tv.z, k4.z, fmaf(tv.w, k4.w, sc[h]))));
        }
    }

    // ---- softmax over 65 tokens (center + 64 neighbors across lanes) ----
    float pmy[H], pctr[H];
    #pragma unroll
    for (int h = 0; h < H; ++h) {
        float mv = sc[h];
        #pragma unroll
        for (int off = 32; off >= 1; off >>= 1)
            mv = fmaxf(mv, __shfl_xor(mv, off));
        mv = fmaxf(mv, s0[h]);
        const float pv = expf(sc[h] - mv);
        const float p0 = expf(s0[h] - mv);
        float sum = pv;
        #pragma unroll
        for (int off = 32; off >= 1; off >>= 1)
            sum += __shfl_xor(sum, off);
        const float inv = 1.0f / (sum + p0);
        pmy[h]  = pv * inv;   // my neighbor token's attn weight
        pctr[h] = p0 * inv;   // center token's attn weight (uniform)
    }
    *reinterpret_cast<float4*>(&P_lds[w][l][0]) = make_float4(pmy[0], pmy[1], pmy[2], pmy[3]);
    *reinterpret_cast<float4*>(&P_lds[w][l][4]) = make_float4(pmy[4], pmy[5], pmy[6], pmy[7]);
    __syncthreads();

    // ---- pass 2: s[h][d] = sum_t attn[h,t] * tokens[t,d], d = d0, d0+1 ----
    float sA[H], sB[H];
    const float cA = c_lds[w][d0], cB = c_lds[w][d0 + 1];
    #pragma unroll
    for (int h = 0; h < H; ++h) {
        sA[h] = pctr[h] * cA;
        sB[h] = pctr[h] * cB;
    }
    const float* nbase = neighbors + (size_t)b * TN * D + d0;
    #pragma unroll 4
    for (int t = 0; t < TN; ++t) {
        const float2 tv = *reinterpret_cast<const float2*>(nbase + (size_t)t * D);
        const float4 pa = *reinterpret_cast<const float4*>(&P_lds[w][t][0]);
        const float4 pb = *reinterpret_cast<const float4*>(&P_lds[w][t][4]);
        sA[0] = fmaf(pa.x, tv.x, sA[0]);  sB[0] = fmaf(pa.x, tv.y, sB[0]);
        sA[1] = fmaf(pa.y, tv.x, sA[1]);  sB[1] = fmaf(pa.y, tv.y, sB[1]);
        sA[2] = fmaf(pa.z, tv.x, sA[2]);  sB[2] = fmaf(pa.z, tv.y, sB[2]);
        sA[3] = fmaf(pa.w, tv.x, sA[3]);  sB[3] = fmaf(pa.w, tv.y, sB[3]);
        sA[4] = fmaf(pb.x, tv.x, sA[4]);  sB[4] = fmaf(pb.x, tv.y, sB[4]);
        sA[5] = fmaf(pb.y, tv.x, sA[5]);  sB[5] = fmaf(pb.y, tv.y, sB[5]);
        sA[6] = fmaf(pb.z, tv.x, sA[6]);  sB[6] = fmaf(pb.z, tv.y, sB[6]);
        sA[7] = fmaf(pb.w, tv.x, sA[7]);  sB[7] = fmaf(pb.w, tv.y, sB[7]);
    }
    __syncthreads();   // qk_lds fully consumed; safe to overwrite with s
    #pragma unroll
    for (int h = 0; h < H; ++h) {
        qk_lds[w][h][d0]     = sA[h];
        qk_lds[w][h][d0 + 1] = sB[h];
    }
    __syncthreads();

    // ---- pass 3: pre-WO out[k] = sum_d s[h(k)][d] * WV[d][k], k = d0, d0+1 ----
    const int h0 = d0 >> 4;   // d0 and d0+1 share a head (d0 even)
    float o0 = 0.f, o1 = 0.f;
    #pragma unroll 8
    for (int d = 0; d < D; ++d) {
        const float sv = qk_lds[w][h0][d];
        const float2 wv = *reinterpret_cast<const float2*>(WV + (size_t)d * D + d0);
        o0 = fmaf(sv, wv.x, o0);
        o1 = fmaf(sv, wv.y, o1);
    }
    q_lds[w][d0]     = o0;
    q_lds[w][d0 + 1] = o1;
    __syncthreads();

    // ---- pass 4: final[e] = sum_k out[k] * WO[k][e], e = d0, d0+1 ----
    float f0 = 0.f, f1 = 0.f;
    #pragma unroll 8
    for (int k4 = 0; k4 < D / 4; ++k4) {
        const float4 ov = *reinterpret_cast<const float4*>(&q_lds[w][k4 * 4]);
        const float oc[4] = {ov.x, ov.y, ov.z, ov.w};
        #pragma unroll
        for (int u = 0; u < 4; ++u) {
            const float2 wo = *reinterpret_cast<const float2*>(WO + (size_t)(k4 * 4 + u) * D + d0);
            f0 = fmaf(oc[u], wo.x, f0);
            f1 = fmaf(oc[u], wo.y, f1);
        }
    }
    *reinterpret_cast<float2*>(out + (size_t)b * D + d0) = make_float2(f0, f1);
}

} // namespace

extern "C" void kernel_launch(void* const* d_in, const int* in_sizes, int n_in,
                              void* d_out, int out_size, void* d_ws, size_t ws_size,
                              hipStream_t stream) {
    const float* center    = (const float*)d_in[0];
    const float* neighbors = (const float*)d_in[1];
    const float* WQ        = (const float*)d_in[2];
    const float* WK        = (const float*)d_in[3];
    const float* WV        = (const float*)d_in[4];
    const float* WO        = (const float*)d_in[5];
    float* outp            = (float*)d_out;

    const int B = in_sizes[0] / D;           // 8192
    dim3 grid(B / WAVES), block(WAVES * 64); // one batch per wave

    hipLaunchKernelGGL(mha_center_kernel, grid, block, 0, stream,
                       center, neighbors, WQ, WK, WV, WO, outp);
}

// Round 3
// 165.199 us; speedup vs baseline: 1.2259x; 1.2259x over previous
//
#include <hip/hip_runtime.h>
#include <math.h>

namespace {

constexpr int D     = 128;
constexpr int H     = 8;
constexpr int TN    = 64;
constexpr int WAVES = 4;
constexpr int SP    = D + 4;   // padded head-row (132) -> conflict-free strided reads

__global__ __launch_bounds__(WAVES * 64)
void mha_center_kernel(const float* __restrict__ center,
                       const float* __restrict__ neighbors,
                       const float* __restrict__ WQ,
                       const float* __restrict__ WK,
                       const float* __restrict__ WV,
                       const float* __restrict__ WO,
                       float* __restrict__ out)
{
    __shared__ float c_lds[WAVES][D];
    __shared__ float q_lds[WAVES][D];        // reused for pre-WO "o"
    __shared__ float qk_lds[WAVES][H][SP];   // reused for weighted sums s
    __shared__ float P_lds[WAVES][TN][8];

    const int w  = threadIdx.x >> 6;
    const int l  = threadIdx.x & 63;
    const int b  = blockIdx.x * WAVES + w;
    const int hi = l >> 5;          // lane half (reduction split)
    const int dd = l & 31;
    const int c4 = dd << 2;         // this lane's 4 output columns in half-split phases

    // ---- early prefetch: first 8 float4 chunks of my token's row (HBM) ----
    const float4* nbrow = reinterpret_cast<const float4*>(neighbors + ((size_t)b * TN + l) * D);
    float4 nrowA[8], nrowB[8];
    #pragma unroll
    for (int i = 0; i < 8; ++i) nrowA[i] = nbrow[i];

    if (l < 32) {
        *reinterpret_cast<float4*>(&c_lds[w][l << 2]) =
            *reinterpret_cast<const float4*>(center + (size_t)b * D + (l << 2));
    }
    __syncthreads();

    // ---- phase A: q[c4..c4+3] = sum_i c[i] * WQ[i][c4..], halves split i ----
    {
        float4 acc = make_float4(0.f, 0.f, 0.f, 0.f);
        const float* wq = WQ + (size_t)(hi * 64) * D + c4;
        float4 wb[2][4];
        #pragma unroll
        for (int i = 0; i < 4; ++i) wb[0][i] = *reinterpret_cast<const float4*>(wq + (size_t)i * D);
        #pragma unroll
        for (int g = 0; g < 16; ++g) {
            const int cur = g & 1, nxt = cur ^ 1;
            if (g < 15) {
                #pragma unroll
                for (int i = 0; i < 4; ++i)
                    wb[nxt][i] = *reinterpret_cast<const float4*>(wq + (size_t)((g + 1) * 4 + i) * D);
            }
            #pragma unroll
            for (int i = 0; i < 4; ++i) {
                const float cc = c_lds[w][hi * 64 + g * 4 + i];
                acc.x = fmaf(cc, wb[cur][i].x, acc.x);
                acc.y = fmaf(cc, wb[cur][i].y, acc.y);
                acc.z = fmaf(cc, wb[cur][i].z, acc.z);
                acc.w = fmaf(cc, wb[cur][i].w, acc.w);
            }
        }
        acc.x += __shfl_xor(acc.x, 32);
        acc.y += __shfl_xor(acc.y, 32);
        acc.z += __shfl_xor(acc.z, 32);
        acc.w += __shfl_xor(acc.w, 32);
        if (hi == 0) {
            acc.x *= 0.25f; acc.y *= 0.25f; acc.z *= 0.25f; acc.w *= 0.25f;
            *reinterpret_cast<float4*>(&q_lds[w][c4]) = acc;
        }
    }
    __syncthreads();

    // ---- phase B: qk[h][d0..d0+1], d0 = 2l; all heads per lane ----
    {
        const int d0 = l << 1;
        const float* wk0 = WK + (size_t)d0 * D;
        const float* wk1 = wk0 + D;
        float4 kb[2][8];
        #pragma unroll
        for (int j = 0; j < 4; ++j) {
            kb[0][j]     = *reinterpret_cast<const float4*>(wk0 + j * 4);
            kb[0][4 + j] = *reinterpret_cast<const float4*>(wk1 + j * 4);
        }
        #pragma unroll
        for (int h = 0; h < 8; ++h) {
            const int cur = h & 1, nxt = cur ^ 1;
            if (h < 7) {
                #pragma unroll
                for (int j = 0; j < 4; ++j) {
                    kb[nxt][j]     = *reinterpret_cast<const float4*>(wk0 + (h + 1) * 16 + j * 4);
                    kb[nxt][4 + j] = *reinterpret_cast<const float4*>(wk1 + (h + 1) * 16 + j * 4);
                }
            }
            float a0 = 0.f, a1 = 0.f;
            #pragma unroll
            for (int j = 0; j < 4; ++j) {
                const float4 qv = *reinterpret_cast<const float4*>(&q_lds[w][h * 16 + j * 4]);
                const float4 k0 = kb[cur][j], k1 = kb[cur][4 + j];
                a0 = fmaf(qv.x, k0.x, fmaf(qv.y, k0.y, fmaf(qv.z, k0.z, fmaf(qv.w, k0.w, a0))));
                a1 = fmaf(qv.x, k1.x, fmaf(qv.y, k1.y, fmaf(qv.z, k1.z, fmaf(qv.w, k1.w, a1))));
            }
            *reinterpret_cast<float2*>(&qk_lds[w][h][d0]) = make_float2(a0, a1);
        }
    }
    __syncthreads();

    // ---- center-token score (butterfly -> uniform) ----
    float s0[8];
    {
        const int d0 = l << 1;
        const float cx = c_lds[w][d0], cy = c_lds[w][d0 + 1];
        #pragma unroll
        for (int h = 0; h < 8; ++h) {
            const float2 qq = *reinterpret_cast<const float2*>(&qk_lds[w][h][d0]);
            float v = qq.x * cx + qq.y * cy;
            #pragma unroll
            for (int off = 32; off >= 1; off >>= 1) v += __shfl_xor(v, off);
            s0[h] = v;
        }
    }

    // ---- pass 1: neighbor scores (token = lane), pipelined 8-deep ----
    float sc[8];
    #pragma unroll
    for (int h = 0; h < 8; ++h) sc[h] = 0.f;

    #define CONSUME_GROUP(ARR, BASE)                                                     \
        _Pragma("unroll")                                                                \
        for (int i = 0; i < 8; ++i) {                                                    \
            const float4 tv = ARR[i];                                                    \
            _Pragma("unroll")                                                            \
            for (int h = 0; h < 8; ++h) {                                                \
                const float4 k4 = *reinterpret_cast<const float4*>(&qk_lds[w][h][(BASE + i) * 4]); \
                sc[h] = fmaf(tv.x, k4.x, fmaf(tv.y, k4.y, fmaf(tv.z, k4.z, fmaf(tv.w, k4.w, sc[h])))); \
            }                                                                            \
        }

    #pragma unroll
    for (int i = 0; i < 8; ++i) nrowB[i] = nbrow[8 + i];
    CONSUME_GROUP(nrowA, 0)
    #pragma unroll
    for (int i = 0; i < 8; ++i) nrowA[i] = nbrow[16 + i];
    CONSUME_GROUP(nrowB, 8)
    #pragma unroll
    for (int i = 0; i < 8; ++i) nrowB[i] = nbrow[24 + i];
    CONSUME_GROUP(nrowA, 16)
    CONSUME_GROUP(nrowB, 24)
    #undef CONSUME_GROUP

    // ---- softmax over 65 tokens ----
    float pctr[8], pmy[8];
    #pragma unroll
    for (int h = 0; h < 8; ++h) {
        float mv = sc[h];
        #pragma unroll
        for (int off = 32; off >= 1; off >>= 1) mv = fmaxf(mv, __shfl_xor(mv, off));
        mv = fmaxf(mv, s0[h]);
        const float pv = expf(sc[h] - mv);
        const float p0 = expf(s0[h] - mv);
        float sum = pv;
        #pragma unroll
        for (int off = 32; off >= 1; off >>= 1) sum += __shfl_xor(sum, off);
        const float inv = 1.0f / (sum + p0);
        pmy[h]  = pv * inv;
        pctr[h] = p0 * inv;
    }
    *reinterpret_cast<float4*>(&P_lds[w][l][0]) = make_float4(pmy[0], pmy[1], pmy[2], pmy[3]);
    *reinterpret_cast<float4*>(&P_lds[w][l][4]) = make_float4(pmy[4], pmy[5], pmy[6], pmy[7]);
    __syncthreads();

    // ---- pass 2: s[h][c4..] = sum_t p[t][h]*tok[t][c4..], halves split t ----
    // BUGFIX (round 2): only the hi==0 half seeds the center-token term;
    // both halves seeding it double-counted the center after the butterfly.
    {
        float4 sac[8];
        const float4 cv4 = *reinterpret_cast<const float4*>(&c_lds[w][c4]);
        const float seed = (hi == 0) ? 1.0f : 0.0f;
        #pragma unroll
        for (int h = 0; h < 8; ++h) {
            const float pc = pctr[h] * seed;
            sac[h].x = pc * cv4.x; sac[h].y = pc * cv4.y;
            sac[h].z = pc * cv4.z; sac[h].w = pc * cv4.w;
        }
        const float* nb2 = neighbors + (size_t)b * TN * D + (size_t)(hi * 32) * D + c4;
        float4 tb[2][8];
        #pragma unroll
        for (int t = 0; t < 8; ++t) tb[0][t] = *reinterpret_cast<const float4*>(nb2 + (size_t)t * D);
        #pragma unroll
        for (int g = 0; g < 4; ++g) {
            const int cur = g & 1, nxt = cur ^ 1;
            if (g < 3) {
                #pragma unroll
                for (int t = 0; t < 8; ++t)
                    tb[nxt][t] = *reinterpret_cast<const float4*>(nb2 + (size_t)((g + 1) * 8 + t) * D);
            }
            #pragma unroll
            for (int t = 0; t < 8; ++t) {
                const int tok = hi * 32 + g * 8 + t;
                const float4 tv = tb[cur][t];
                const float4 pa = *reinterpret_cast<const float4*>(&P_lds[w][tok][0]);
                const float4 pb = *reinterpret_cast<const float4*>(&P_lds[w][tok][4]);
                const float p8[8] = {pa.x, pa.y, pa.z, pa.w, pb.x, pb.y, pb.z, pb.w};
                #pragma unroll
                for (int h = 0; h < 8; ++h) {
                    sac[h].x = fmaf(p8[h], tv.x, sac[h].x);
                    sac[h].y = fmaf(p8[h], tv.y, sac[h].y);
                    sac[h].z = fmaf(p8[h], tv.z, sac[h].z);
                    sac[h].w = fmaf(p8[h], tv.w, sac[h].w);
                }
            }
        }
        #pragma unroll
        for (int h = 0; h < 8; ++h) {
            sac[h].x += __shfl_xor(sac[h].x, 32);
            sac[h].y += __shfl_xor(sac[h].y, 32);
            sac[h].z += __shfl_xor(sac[h].z, 32);
            sac[h].w += __shfl_xor(sac[h].w, 32);
        }
        __syncthreads();   // all intra-wave readers of qk_lds are done; cheap safety
        if (hi == 0) {
            #pragma unroll
            for (int h = 0; h < 8; ++h)
                *reinterpret_cast<float4*>(&qk_lds[w][h][c4]) = sac[h];
        }
    }
    __syncthreads();

    // ---- pass 3: o[c4..] = sum_d s[h(c4)][d] * WV[d][c4..], halves split d ----
    {
        const int h0 = dd >> 2;
        float4 oac = make_float4(0.f, 0.f, 0.f, 0.f);
        const float* wv = WV + (size_t)(hi * 64) * D + c4;
        float4 vb[2][4];
        #pragma unroll
        for (int i = 0; i < 4; ++i) vb[0][i] = *reinterpret_cast<const float4*>(wv + (size_t)i * D);
        #pragma unroll
        for (int g = 0; g < 16; ++g) {
            const int cur = g & 1, nxt = cur ^ 1;
            if (g < 15) {
                #pragma unroll
                for (int i = 0; i < 4; ++i)
                    vb[nxt][i] = *reinterpret_cast<const float4*>(wv + (size_t)((g + 1) * 4 + i) * D);
            }
            #pragma unroll
            for (int i = 0; i < 4; ++i) {
                const float sv = qk_lds[w][h0][hi * 64 + g * 4 + i];
                oac.x = fmaf(sv, vb[cur][i].x, oac.x);
                oac.y = fmaf(sv, vb[cur][i].y, oac.y);
                oac.z = fmaf(sv, vb[cur][i].z, oac.z);
                oac.w = fmaf(sv, vb[cur][i].w, oac.w);
            }
        }
        oac.x += __shfl_xor(oac.x, 32);
        oac.y += __shfl_xor(oac.y, 32);
        oac.z += __shfl_xor(oac.z, 32);
        oac.w += __shfl_xor(oac.w, 32);
        if (hi == 0) *reinterpret_cast<float4*>(&q_lds[w][c4]) = oac;
    }
    __syncthreads();

    // ---- pass 4: final[c4..] = sum_k o[k] * WO[k][c4..], halves split k ----
    {
        float4 fac = make_float4(0.f, 0.f, 0.f, 0.f);
        const float* wo = WO + (size_t)(hi * 64) * D + c4;
        float4 ob[2][4];
        #pragma unroll
        for (int i = 0; i < 4; ++i) ob[0][i] = *reinterpret_cast<const float4*>(wo + (size_t)i * D);
        #pragma unroll
        for (int g = 0; g < 16; ++g) {
            const int cur = g & 1, nxt = cur ^ 1;
            if (g < 15) {
                #pragma unroll
                for (int i = 0; i < 4; ++i)
                    ob[nxt][i] = *reinterpret_cast<const float4*>(wo + (size_t)((g + 1) * 4 + i) * D);
            }
            #pragma unroll
            for (int i = 0; i < 4; ++i) {
                const float ov = q_lds[w][hi * 64 + g * 4 + i];
                fac.x = fmaf(ov, ob[cur][i].x, fac.x);
                fac.y = fmaf(ov, ob[cur][i].y, fac.y);
                fac.z = fmaf(ov, ob[cur][i].z, fac.z);
                fac.w = fmaf(ov, ob[cur][i].w, fac.w);
            }
        }
        fac.x += __shfl_xor(fac.x, 32);
        fac.y += __shfl_xor(fac.y, 32);
        fac.z += __shfl_xor(fac.z, 32);
        fac.w += __shfl_xor(fac.w, 32);
        if (hi == 0)
            *reinterpret_cast<float4*>(out + (size_t)b * D + c4) = fac;
    }
}

} // namespace

extern "C" void kernel_launch(void* const* d_in, const int* in_sizes, int n_in,
                              void* d_out, int out_size, void* d_ws, size_t ws_size,
                              hipStream_t stream) {
    const float* center    = (const float*)d_in[0];
    const float* neighbors = (const float*)d_in[1];
    const float* WQ        = (const float*)d_in[2];
    const float* WK        = (const float*)d_in[3];
    const float* WV        = (const float*)d_in[4];
    const float* WO        = (const float*)d_in[5];
    float* outp            = (float*)d_out;

    const int B = in_sizes[0] / D;
    dim3 grid(B / WAVES), block(WAVES * 64);

    hipLaunchKernelGGL(mha_center_kernel, grid, block, 0, stream,
                       center, neighbors, WQ, WK, WV, WO, outp);
}